// Round 10
// baseline (96.415 us; speedup 1.0000x reference)
//
#include <hip/hip_runtime.h>

// ---------- types ----------
using f32x4  = __attribute__((ext_vector_type(4))) float;
using bf16x8 = __attribute__((ext_vector_type(8))) short;   // 8 bf16 in 4 VGPRs

__device__ __forceinline__ unsigned short f2bf(float f) {
    union { float f; unsigned int u; } v; v.f = f;
    unsigned int r = v.u + 0x7fffu + ((v.u >> 16) & 1u);  // RNE
    return (unsigned short)(r >> 16);
}

__device__ __forceinline__ float bf2f(unsigned short u) {
    union { unsigned int u; float f; } v; v.u = ((unsigned int)u) << 16;
    return v.f;
}

// ---------- transpose D [16][256c][256q] f32 -> Dt [16][256q][256c] bf16; zero stats ----------
__global__ __launch_bounds__(256) void transposeD(
    const float* __restrict__ x, unsigned short* __restrict__ y, float* __restrict__ stats) {
    __shared__ float tile[32][33];
    int b  = blockIdx.z;
    int p0 = blockIdx.x * 32;      // q tile
    int c0 = blockIdx.y * 32;      // c tile
    const float* xb = x + (size_t)b * 256 * 256;
    unsigned short* yb = y + (size_t)b * 256 * 256;
    int tx = threadIdx.x, ty = threadIdx.y;
    #pragma unroll
    for (int i = 0; i < 32; i += 8)
        tile[ty + i][tx] = xb[(size_t)(c0 + ty + i) * 256 + (p0 + tx)];
    __syncthreads();
    int tid = ty * 32 + tx;
    #pragma unroll
    for (int k = 0; k < 2; ++k) {
        int wi = tid * 2 + k;          // 0..511
        int pl = wi >> 4;              // local q row
        int cp = wi & 15;              // c-pair
        unsigned short lo = f2bf(tile[2 * cp][pl]);
        unsigned short hi = f2bf(tile[2 * cp + 1][pl]);
        unsigned int packed = (unsigned int)lo | ((unsigned int)hi << 16);
        *reinterpret_cast<unsigned int*>(&yb[(size_t)(p0 + pl) * 256 + (c0 + 2 * cp)]) = packed;
    }
    if (blockIdx.x == 0 && blockIdx.y == 0 && blockIdx.z == 0 && tid == 0) {
        stats[0] = 0.f;
        stats[1] = 0.f;
    }
}

// ---------- fused conv (R4-exact) + 64 prefetch-role blocks ----------
// Blocks 0..63: sequentially sweep S (channel-clean) to pull it into L3 while
// conv blocks (64..1087) consume it with their channel-confined strided reads.
// Conv block = (b, image row r). Computes G[p=r*64..+64)[q=0..256), writes
// 16-tap diagonal sums non-atomically to P[b][r][i][x].
// LDS A layout: byte(p,c) = p*512 + (((c>>3) ^ (p&15) ^ (p>>4)) << 4) + (c&7)*2
__global__ __launch_bounds__(256, 4) void conv_fused(
    const float* __restrict__ S,             // [16][256][64][64] f32
    const unsigned short* __restrict__ Dt,   // [16][256q][256c] bf16
    float* __restrict__ P,                   // [16][64][16][52] f32 partials
    float* __restrict__ scratch) {           // 64*256 floats (prefetch sums; dead)
    __shared__ __align__(16) char lds[64 * 262 * 2];
    char* base = lds;

    int blk = blockIdx.x;
    int tid = threadIdx.x;

    if (blk < 64) {
        // ---- prefetch role: sequential sweep of S, 256KB-contiguous front ----
        const f32x4* p4 = reinterpret_cast<const f32x4*>(S);
        const size_t total4 = (size_t)16 * 256 * 64 * 64 / 4;   // 4,194,304
        f32x4 a = {0.f, 0.f, 0.f, 0.f};
        for (size_t i = (size_t)blk * 256 + tid; i < total4; i += 64 * 256)
            a += p4[i];
        scratch[blk * 256 + tid] = a[0] + a[1] + a[2] + a[3];
        return;
    }

    int cblk = blk - 64;
    int b = cblk >> 6;
    int r = cblk & 63;

    int w    = tid >> 6;          // wave 0..3
    int lane = tid & 63;
    int m    = lane & 15;
    int kg   = lane >> 4;
    const unsigned short* Db = Dt + ((size_t)(b * 256 + 64 * w)) * 256;

    // ---- stage: issue ALL 16 global loads ----
    int px = tid & 15;
    int cq = tid >> 4;
    const float* Sbr = S + ((size_t)b * 256 * 64 + r) * 64;   // + c*4096 + p

    f32x4 v[4][4];
    #pragma unroll
    for (int rho = 0; rho < 4; ++rho) {
        int c0 = rho * 64 + 4 * cq;
        #pragma unroll
        for (int j = 0; j < 4; ++j)
            v[rho][j] = *reinterpret_cast<const f32x4*>(Sbr + (size_t)(c0 + j) * 4096 + 4 * px);
    }
    // prefetch B for K-step 0 (stays in flight across the lgkm-only barrier)
    bf16x8 bcur[4];
    #pragma unroll
    for (int n = 0; n < 4; ++n)
        bcur[n] = *reinterpret_cast<const bf16x8*>(Db + (size_t)(16 * n + m) * 256 + kg * 8);
    __builtin_amdgcn_sched_barrier(0);   // keep all loads issued before any consumption

    // convert + in-register 4x4 transpose + ds_write_b64
    #pragma unroll
    for (int rho = 0; rho < 4; ++rho) {
        int slot = 8 * rho + (cq >> 1);
        int half = cq & 1;
        #pragma unroll
        for (int e = 0; e < 4; ++e) {
            int p = 4 * px + e;
            int swz = (p & 15) ^ (p >> 4);
            ushort4 o;
            o.x = f2bf(v[rho][0][e]);
            o.y = f2bf(v[rho][1][e]);
            o.z = f2bf(v[rho][2][e]);
            o.w = f2bf(v[rho][3][e]);
            *reinterpret_cast<ushort4*>(base + p * 512 + ((slot ^ swz) << 4) + half * 8) = o;
        }
    }
    // barrier that waits only for LDS writes; B-prefetch (vmcnt) stays in flight
    asm volatile("s_waitcnt lgkmcnt(0)" ::: "memory");
    __builtin_amdgcn_s_barrier();

    // ---- GEMM: wave w computes q in [64w, 64w+64), all 64 p rows, K=256 ----
    f32x4 acc[4][4];
    #pragma unroll
    for (int i = 0; i < 4; ++i)
        #pragma unroll
        for (int j = 0; j < 4; ++j)
            acc[i][j] = f32x4{0.f, 0.f, 0.f, 0.f};

    #pragma unroll
    for (int step = 0; step < 8; ++step) {
        bf16x8 bnext[4];
        if (step < 7) {
            #pragma unroll
            for (int n = 0; n < 4; ++n)
                bnext[n] = *reinterpret_cast<const bf16x8*>(
                    Db + (size_t)(16 * n + m) * 256 + (step + 1) * 32 + kg * 8);
        }
        bf16x8 af[4];
        #pragma unroll
        for (int pa = 0; pa < 4; ++pa) {
            int p = 16 * pa + m;
            int slot = (4 * step + kg) ^ m ^ pa;     // (c>>3) ^ (p&15) ^ (p>>4)
            af[pa] = *reinterpret_cast<const bf16x8*>(base + p * 512 + (slot << 4));
        }
        #pragma unroll
        for (int pa = 0; pa < 4; ++pa)
            #pragma unroll
            for (int n = 0; n < 4; ++n)
                acc[pa][n] = __builtin_amdgcn_mfma_f32_16x16x32_bf16(af[pa], bcur[n], acc[pa][n], 0, 0, 0);
        #pragma unroll
        for (int n = 0; n < 4; ++n)
            bcur[n] = bnext[n];
    }

    __syncthreads();   // all waves done reading At before overwrite

    // ---- dump G tile to LDS as bf16: gt[64 p][262] ----
    unsigned short* gt = (unsigned short*)base;
    #pragma unroll
    for (int pa = 0; pa < 4; ++pa)
        #pragma unroll
        for (int n = 0; n < 4; ++n)
            #pragma unroll
            for (int t = 0; t < 4; ++t) {
                int row = 16 * pa + 4 * kg + t;        // p local (spatial col)
                int col = 64 * w + 16 * n + m;         // q
                gt[row * 262 + col] = f2bf(acc[pa][n][t]);
            }
    __syncthreads();

    // ---- partials: P[b][r][i][x] = sum_j G[x+j][16i+j] (no atomics) ----
    int ilo = (r > 48) ? (r - 48) : 0;
    int ihi = (r < 15) ? r : 15;
    int total = (ihi - ilo + 1) * 49;
    for (int o = tid; o < total; o += 256) {
        int i = ilo + o / 49;
        int x = o % 49;
        float s = 0.f;
        int qb = 16 * i;
        #pragma unroll
        for (int j = 0; j < 16; ++j)
            s += bf2f(gt[(x + j) * 262 + qb + j]);
        P[((size_t)((b * 64 + r) * 16 + i)) * 52 + x] = s;
    }
}

// ---------- reduce partials + global stats: mm[b][y][x] = sum_i P[b][y+i][i][x] ----------
__global__ __launch_bounds__(256) void reduce_kernel(
    const float* __restrict__ P, float* __restrict__ mm, float* __restrict__ stats) {
    int idx = blockIdx.x * 256 + threadIdx.x;
    float s = 0.f;
    if (idx < 38416) {
        int b  = idx / 2401;
        int yx = idx % 2401;
        int y  = yx / 49;
        int x  = yx % 49;
        #pragma unroll
        for (int i = 0; i < 16; ++i)
            s += P[((size_t)((b * 64 + y + i) * 16 + i)) * 52 + x];
        mm[idx] = s;
    }
    __shared__ float rs[256];
    __shared__ float rq[256];
    int tid = threadIdx.x;
    rs[tid] = (idx < 38416) ? s : 0.f;
    rq[tid] = (idx < 38416) ? s * s : 0.f;
    __syncthreads();
    for (int st = 128; st > 0; st >>= 1) {
        if (tid < st) { rs[tid] += rs[tid + st]; rq[tid] += rq[tid + st]; }
        __syncthreads();
    }
    if (tid == 0) {
        atomicAdd(&stats[0], rs[0]);
        atomicAdd(&stats[1], rq[0]);
    }
}

// ---------- fallback naive conv (tiny ws) ----------
__global__ __launch_bounds__(256) void conv_naive(
    const float* __restrict__ S, const float* __restrict__ D, float* __restrict__ mm) {
    int blk = blockIdx.x;            // b*2401 + y*49 + x
    int b = blk / 2401;
    int yx = blk % 2401;
    int y = yx / 49, x = yx % 49;
    int c = threadIdx.x;
    const float* Sp = S + (((size_t)b * 256 + c) * 64 + y) * 64 + x;
    const float* Dp = D + ((size_t)b * 256 + c) * 256;
    float s = 0.f;
    #pragma unroll
    for (int i = 0; i < 16; ++i)
        #pragma unroll 4
        for (int j = 0; j < 16; ++j)
            s += Sp[i * 64 + j] * Dp[i * 16 + j];
    __shared__ float red[256];
    red[c] = s;
    __syncthreads();
    for (int st = 128; st > 0; st >>= 1) {
        if (c < st) red[c] += red[c + st];
        __syncthreads();
    }
    if (c == 0) mm[blk] = red[0];
}

// ---------- fallback stats: raw sums ----------
__global__ __launch_bounds__(1024) void stats_kernel(
    const float* __restrict__ mm, float* __restrict__ stats) {
    __shared__ float ssum[1024];
    __shared__ float ssq[1024];
    int tid = threadIdx.x;
    float s = 0.f, q = 0.f;
    for (int i = tid; i < 38416; i += 1024) {
        float v = mm[i];
        s += v; q += v * v;
    }
    ssum[tid] = s; ssq[tid] = q;
    __syncthreads();
    for (int st = 512; st > 0; st >>= 1) {
        if (tid < st) { ssum[tid] += ssum[tid + st]; ssq[tid] += ssq[tid + st]; }
        __syncthreads();
    }
    if (tid == 0) {
        stats[0] = ssum[0];
        stats[1] = ssq[0];
    }
}

// ---------- normalize + bilinear 49x49 -> 256x256 (stats are raw sums) ----------
__global__ __launch_bounds__(256) void bilinear_kernel(
    const float* __restrict__ mm, const float* __restrict__ stats,
    const float* __restrict__ gamma, const float* __restrict__ beta,
    float* __restrict__ out) {
    int idx = blockIdx.x * 256 + threadIdx.x;   // 16*256*256 = 1,048,576
    int b  = idx >> 16;
    int oy = (idx >> 8) & 255;
    int ox = idx & 255;
    const float scale = 49.0f / 256.0f;
    float cy = fminf(fmaxf((oy + 0.5f) * scale - 0.5f, 0.0f), 48.0f);
    int y0 = (int)cy; int y1 = min(y0 + 1, 48); float wy = cy - (float)y0;
    float cx = fminf(fmaxf((ox + 0.5f) * scale - 0.5f, 0.0f), 48.0f);
    int x0 = (int)cx; int x1 = min(x0 + 1, 48); float wx = cx - (float)x0;
    const float* mb = mm + (size_t)b * 2401;
    float v00 = mb[y0 * 49 + x0];
    float v01 = mb[y0 * 49 + x1];
    float v10 = mb[y1 * 49 + x0];
    float v11 = mb[y1 * 49 + x1];
    float r0 = v00 * (1.f - wy) + v10 * wy;
    float r1 = v01 * (1.f - wy) + v11 * wy;
    float v  = r0 * (1.f - wx) + r1 * wx;
    const float invN = 1.0f / 38416.0f;
    float mean = stats[0] * invN;
    float var  = stats[1] * invN - mean * mean;
    float rstd = rsqrtf(var + 1e-5f);
    v = (v - mean) * rstd * gamma[0] + beta[0];
    out[idx] = v;
}

extern "C" void kernel_launch(void* const* d_in, const int* in_sizes, int n_in,
                              void* d_out, int out_size, void* d_ws, size_t ws_size,
                              hipStream_t stream) {
    const float* S     = (const float*)d_in[0];   // (16,256,64,64)
    const float* D     = (const float*)d_in[1];   // (16,256,16,16)
    const float* gamma = (const float*)d_in[2];   // (1,)
    const float* beta  = (const float*)d_in[3];   // (1,)
    float* out = (float*)d_out;                   // (16,1,256,256)

    char* ws = (char*)d_ws;
    const size_t sizeDt = (size_t)16 * 256 * 256 * 2;        // 2,097,152
    const size_t sizeMm = (size_t)38416 * 4;                 //   153,664
    const size_t sizeP  = (size_t)16 * 64 * 16 * 52 * 4;     // 3,407,872
    const size_t sizeScr= (size_t)64 * 256 * 4;              //    65,536
    const size_t offDt = 0;
    const size_t offMm = offDt + sizeDt;
    const size_t offStats = offMm + sizeMm;
    const size_t offP = (offStats + 2 * sizeof(float) + 255) & ~(size_t)255;
    const size_t offScr = offP + sizeP;
    const size_t needFast = offScr + sizeScr;

    bool fast = (ws_size >= needFast);
    float* mm;
    float* stats;
    if (fast) {
        mm    = (float*)(ws + offMm);
        stats = (float*)(ws + offStats);
    } else {
        mm    = (float*)ws;
        stats = (float*)(ws + sizeMm);
    }

    if (fast) {
        unsigned short* Dt = (unsigned short*)(ws + offDt);
        float* P = (float*)(ws + offP);
        float* scr = (float*)(ws + offScr);
        transposeD<<<dim3(8, 8, 16), dim3(32, 8), 0, stream>>>(D, Dt, stats);
        conv_fused<<<1088, 256, 0, stream>>>(S, Dt, P, scr);
        reduce_kernel<<<151, 256, 0, stream>>>(P, mm, stats);
    } else {
        conv_naive<<<16 * 2401, 256, 0, stream>>>(S, D, mm);
        stats_kernel<<<1, 1024, 0, stream>>>(mm, stats);
    }
    bilinear_kernel<<<4096, 256, 0, stream>>>(mm, stats, gamma, beta, out);
}

// Round 11
// 46.207 us; speedup vs baseline: 2.0866x; 2.0866x over previous
//
#include <hip/hip_runtime.h>

// ---------- types ----------
using f32x4  = __attribute__((ext_vector_type(4))) float;
using bf16x8 = __attribute__((ext_vector_type(8))) short;            // 8 bf16
using u16x8  = __attribute__((ext_vector_type(8))) unsigned short;   // 16 B

__device__ __forceinline__ unsigned short f2bf(float f) {
    union { float f; unsigned int u; } v; v.f = f;
    unsigned int r = v.u + 0x7fffu + ((v.u >> 16) & 1u);  // RNE
    return (unsigned short)(r >> 16);
}

__device__ __forceinline__ float bf2f(unsigned short u) {
    union { unsigned int u; float f; } v; v.u = ((unsigned int)u) << 16;
    return v.f;
}

// ---------- transpose D [16][256c][256q] f32 -> Dt [16][256q][256c] bf16; zero stats ----------
__global__ __launch_bounds__(256) void transposeD(
    const float* __restrict__ x, unsigned short* __restrict__ y, float* __restrict__ stats) {
    __shared__ float tile[32][33];
    int b  = blockIdx.z;
    int p0 = blockIdx.x * 32;      // q tile
    int c0 = blockIdx.y * 32;      // c tile
    const float* xb = x + (size_t)b * 256 * 256;
    unsigned short* yb = y + (size_t)b * 256 * 256;
    int tx = threadIdx.x, ty = threadIdx.y;
    #pragma unroll
    for (int i = 0; i < 32; i += 8)
        tile[ty + i][tx] = xb[(size_t)(c0 + ty + i) * 256 + (p0 + tx)];
    __syncthreads();
    int tid = ty * 32 + tx;
    #pragma unroll
    for (int k = 0; k < 2; ++k) {
        int wi = tid * 2 + k;          // 0..511
        int pl = wi >> 4;              // local q row
        int cp = wi & 15;              // c-pair
        unsigned short lo = f2bf(tile[2 * cp][pl]);
        unsigned short hi = f2bf(tile[2 * cp + 1][pl]);
        unsigned int packed = (unsigned int)lo | ((unsigned int)hi << 16);
        *reinterpret_cast<unsigned int*>(&yb[(size_t)(p0 + pl) * 256 + (c0 + 2 * cp)]) = packed;
    }
    if (blockIdx.x == 0 && blockIdx.y == 0 && blockIdx.z == 0 && tid == 0) {
        stats[0] = 0.f;
        stats[1] = 0.f;
    }
}

#define BARRIER() do { \
    asm volatile("s_waitcnt lgkmcnt(0)" ::: "memory"); \
    __builtin_amdgcn_s_barrier(); \
    __builtin_amdgcn_sched_barrier(0); } while (0)

// ---------- conv, r-quad tiling: 1KB-contiguous staging chunks ----------
// Block = (b, rq). Stages rows r0..r0+3 of all 256 planes as 4 swizzled 32KB
// LDS images (one wave-instruction = one 1KB chunk = 4 rows x 64x of one plane).
// Image layout: byte(p,c) = p*512 + (((c>>3) ^ (p&15) ^ (p>>4) ^ t)<<4) + (c&7)*2
// Per image t: GEMM (wave w owns q in [32w,32w+32)), shifted-column gt overlay
// (gt[q*64 + ((p-(q&15))&63)]), diagonal gather -> P[b][r][i][x].
__global__ __launch_bounds__(512, 2) void conv_rg4(
    const float* __restrict__ S,             // [16][256][64][64] f32
    const unsigned short* __restrict__ Dt,   // [16][256q][256c] bf16
    float* __restrict__ P) {                 // [16][64][16][52] f32 partials
    __shared__ __align__(16) char lds[4 * 32768];   // 128 KB

    int b  = blockIdx.x >> 4;
    int rq = blockIdx.x & 15;
    int r0 = rq * 4;
    int tid = threadIdx.x;

    int wv = tid >> 6;            // wave 0..7
    int l  = tid & 63;
    int m  = l & 15;              // x-quad / GEMM row-in-16
    int kg = l >> 4;              // staging row t / GEMM k-group

    // ---- stage: 32 loads/thread; each wave instruction = 1KB contiguous chunk ----
    const float* Sb = S + (size_t)b * 1048576 + (size_t)(r0 + kg) * 64 + 4 * m;
    f32x4 v[32];
    #pragma unroll
    for (int k = 0; k < 32; ++k)
        v[k] = *reinterpret_cast<const f32x4*>(Sb + (size_t)(32 * wv + k) * 4096);

    // ---- B fragments: load once, reuse across all 4 images ----
    const unsigned short* Db = Dt + (size_t)(b * 256 + 32 * wv) * 256;
    bf16x8 Bf[8][2];
    #pragma unroll
    for (int st = 0; st < 8; ++st)
        #pragma unroll
        for (int n = 0; n < 2; ++n)
            Bf[st][n] = *reinterpret_cast<const bf16x8*>(
                Db + (size_t)(16 * n + m) * 256 + st * 32 + kg * 8);
    __builtin_amdgcn_sched_barrier(0);   // all loads issued before any consumption

    // ---- convert + swizzled ds_write_b128 (image = kg) ----
    {
        char* img = lds + kg * 32768;
        #pragma unroll
        for (int o = 0; o < 4; ++o) {
            int oct = 4 * wv + o;
            #pragma unroll
            for (int e = 0; e < 4; ++e) {
                int p = 4 * m + e;
                int slot = (oct ^ (p & 15) ^ (p >> 4) ^ kg) & 31;
                u16x8 u;
                #pragma unroll
                for (int cj = 0; cj < 8; ++cj) u[cj] = f2bf(v[8 * o + cj][e]);
                *reinterpret_cast<u16x8*>(img + p * 512 + (slot << 4)) = u;
            }
        }
    }
    BARRIER();   // all images staged

    // ---- per-image: GEMM -> gt dump -> gather ----
    #pragma unroll
    for (int t2 = 0; t2 < 4; ++t2) {
        char* img = lds + t2 * 32768;
        f32x4 acc[4][2];
        #pragma unroll
        for (int i = 0; i < 4; ++i)
            #pragma unroll
            for (int j = 0; j < 2; ++j)
                acc[i][j] = f32x4{0.f, 0.f, 0.f, 0.f};

        #pragma unroll
        for (int st = 0; st < 8; ++st) {
            bf16x8 af[4];
            #pragma unroll
            for (int pa = 0; pa < 4; ++pa) {
                int p = 16 * pa + m;
                int slot = ((4 * st + kg) ^ m ^ pa ^ t2) & 31;
                af[pa] = *reinterpret_cast<const bf16x8*>(img + p * 512 + (slot << 4));
            }
            #pragma unroll
            for (int pa = 0; pa < 4; ++pa)
                #pragma unroll
                for (int n = 0; n < 2; ++n)
                    acc[pa][n] = __builtin_amdgcn_mfma_f32_16x16x32_bf16(af[pa], Bf[st][n], acc[pa][n], 0, 0, 0);
        }
        BARRIER();   // all reads of img done before gt overwrite

        // dump shifted-column gt into the consumed image
        unsigned short* gt = (unsigned short*)img;
        #pragma unroll
        for (int pa = 0; pa < 4; ++pa)
            #pragma unroll
            for (int n = 0; n < 2; ++n) {
                int q = 32 * wv + 16 * n + m;
                #pragma unroll
                for (int e = 0; e < 4; ++e) {
                    int p = 16 * pa + 4 * kg + e;
                    gt[q * 64 + ((p - m) & 63)] = f2bf(acc[pa][n][e]);
                }
            }
        BARRIER();   // gt complete

        // gather: P[b][r][i][x] = sum_j gt[(16i+j)*64 + x]
        int r = r0 + t2;
        int ilo = (r > 48) ? (r - 48) : 0;
        int ihi = (r < 15) ? r : 15;
        int total = (ihi - ilo + 1) * 49;
        for (int o = tid; o < total; o += 512) {
            int i = ilo + o / 49;
            int x = o % 49;
            float s = 0.f;
            int qb = 16 * i;
            #pragma unroll
            for (int j = 0; j < 16; ++j)
                s += bf2f(gt[(qb + j) * 64 + x]);
            P[((size_t)((b * 64 + r) * 16 + i)) * 52 + x] = s;
        }
        // no barrier needed: next iteration touches img(t2+1) only; gt(t2) is dead
    }
}

// ---------- reduce partials + global stats: mm[b][y][x] = sum_i P[b][y+i][i][x] ----------
__global__ __launch_bounds__(256) void reduce_kernel(
    const float* __restrict__ P, float* __restrict__ mm, float* __restrict__ stats) {
    int idx = blockIdx.x * 256 + threadIdx.x;
    float s = 0.f;
    if (idx < 38416) {
        int b  = idx / 2401;
        int yx = idx % 2401;
        int y  = yx / 49;
        int x  = yx % 49;
        #pragma unroll
        for (int i = 0; i < 16; ++i)
            s += P[((size_t)((b * 64 + y + i) * 16 + i)) * 52 + x];
        mm[idx] = s;
    }
    __shared__ float rs[256];
    __shared__ float rq[256];
    int tid = threadIdx.x;
    rs[tid] = (idx < 38416) ? s : 0.f;
    rq[tid] = (idx < 38416) ? s * s : 0.f;
    __syncthreads();
    for (int st = 128; st > 0; st >>= 1) {
        if (tid < st) { rs[tid] += rs[tid + st]; rq[tid] += rq[tid + st]; }
        __syncthreads();
    }
    if (tid == 0) {
        atomicAdd(&stats[0], rs[0]);
        atomicAdd(&stats[1], rq[0]);
    }
}

// ---------- fallback naive conv (tiny ws) ----------
__global__ __launch_bounds__(256) void conv_naive(
    const float* __restrict__ S, const float* __restrict__ D, float* __restrict__ mm) {
    int blk = blockIdx.x;            // b*2401 + y*49 + x
    int b = blk / 2401;
    int yx = blk % 2401;
    int y = yx / 49, x = yx % 49;
    int c = threadIdx.x;
    const float* Sp = S + (((size_t)b * 256 + c) * 64 + y) * 64 + x;
    const float* Dp = D + ((size_t)b * 256 + c) * 256;
    float s = 0.f;
    #pragma unroll
    for (int i = 0; i < 16; ++i)
        #pragma unroll 4
        for (int j = 0; j < 16; ++j)
            s += Sp[i * 64 + j] * Dp[i * 16 + j];
    __shared__ float red[256];
    red[c] = s;
    __syncthreads();
    for (int st = 128; st > 0; st >>= 1) {
        if (c < st) red[c] += red[c + st];
        __syncthreads();
    }
    if (c == 0) mm[blk] = red[0];
}

// ---------- fallback stats: raw sums ----------
__global__ __launch_bounds__(1024) void stats_kernel(
    const float* __restrict__ mm, float* __restrict__ stats) {
    __shared__ float ssum[1024];
    __shared__ float ssq[1024];
    int tid = threadIdx.x;
    float s = 0.f, q = 0.f;
    for (int i = tid; i < 38416; i += 1024) {
        float v = mm[i];
        s += v; q += v * v;
    }
    ssum[tid] = s; ssq[tid] = q;
    __syncthreads();
    for (int st = 512; st > 0; st >>= 1) {
        if (tid < st) { ssum[tid] += ssum[tid + st]; ssq[tid] += ssq[tid + st]; }
        __syncthreads();
    }
    if (tid == 0) {
        stats[0] = ssum[0];
        stats[1] = ssq[0];
    }
}

// ---------- normalize + bilinear 49x49 -> 256x256 (float4 stores; stats are raw sums) ----------
__global__ __launch_bounds__(256) void bilinear_kernel(
    const float* __restrict__ mm, const float* __restrict__ stats,
    const float* __restrict__ gamma, const float* __restrict__ beta,
    float* __restrict__ out) {
    int idx4 = blockIdx.x * 256 + threadIdx.x;   // 262144 quads
    int b   = idx4 >> 14;
    int rem = idx4 & 16383;
    int oy  = rem >> 6;
    int ox0 = (rem & 63) << 2;
    const float scale = 49.0f / 256.0f;
    float cy = fminf(fmaxf((oy + 0.5f) * scale - 0.5f, 0.0f), 48.0f);
    int y0 = (int)cy; int y1 = min(y0 + 1, 48); float wy = cy - (float)y0;
    const float* mb = mm + (size_t)b * 2401;
    const float invN = 1.0f / 38416.0f;
    float mean = stats[0] * invN;
    float var  = stats[1] * invN - mean * mean;
    float rstd = rsqrtf(var + 1e-5f);
    float g = gamma[0], be = beta[0];
    f32x4 res;
    #pragma unroll
    for (int e = 0; e < 4; ++e) {
        int ox = ox0 + e;
        float cx = fminf(fmaxf((ox + 0.5f) * scale - 0.5f, 0.0f), 48.0f);
        int x0 = (int)cx; int x1 = min(x0 + 1, 48); float wx = cx - (float)x0;
        float v00 = mb[y0 * 49 + x0];
        float v01 = mb[y0 * 49 + x1];
        float v10 = mb[y1 * 49 + x0];
        float v11 = mb[y1 * 49 + x1];
        float r0 = v00 * (1.f - wy) + v10 * wy;
        float r1 = v01 * (1.f - wy) + v11 * wy;
        float vv = r0 * (1.f - wx) + r1 * wx;
        res[e] = (vv - mean) * rstd * g + be;
    }
    *reinterpret_cast<f32x4*>(out + ((size_t)b << 16) + (oy << 8) + ox0) = res;
}

extern "C" void kernel_launch(void* const* d_in, const int* in_sizes, int n_in,
                              void* d_out, int out_size, void* d_ws, size_t ws_size,
                              hipStream_t stream) {
    const float* S     = (const float*)d_in[0];   // (16,256,64,64)
    const float* D     = (const float*)d_in[1];   // (16,256,16,16)
    const float* gamma = (const float*)d_in[2];   // (1,)
    const float* beta  = (const float*)d_in[3];   // (1,)
    float* out = (float*)d_out;                   // (16,1,256,256)

    char* ws = (char*)d_ws;
    const size_t sizeDt = (size_t)16 * 256 * 256 * 2;        // 2,097,152
    const size_t sizeMm = (size_t)38416 * 4;                 //   153,664
    const size_t sizeP  = (size_t)16 * 64 * 16 * 52 * 4;     // 3,407,872
    const size_t offDt = 0;
    const size_t offMm = offDt + sizeDt;
    const size_t offStats = offMm + sizeMm;
    const size_t offP = (offStats + 2 * sizeof(float) + 255) & ~(size_t)255;
    const size_t needFast = offP + sizeP;

    bool fast = (ws_size >= needFast);
    float* mm;
    float* stats;
    if (fast) {
        mm    = (float*)(ws + offMm);
        stats = (float*)(ws + offStats);
    } else {
        mm    = (float*)ws;
        stats = (float*)(ws + sizeMm);
    }

    if (fast) {
        unsigned short* Dt = (unsigned short*)(ws + offDt);
        float* P = (float*)(ws + offP);
        transposeD<<<dim3(8, 8, 16), dim3(32, 8), 0, stream>>>(D, Dt, stats);
        conv_rg4<<<256, 512, 0, stream>>>(S, Dt, P);
        reduce_kernel<<<151, 256, 0, stream>>>(P, mm, stats);
    } else {
        conv_naive<<<16 * 2401, 256, 0, stream>>>(S, D, mm);
        stats_kernel<<<1, 1024, 0, stream>>>(mm, stats);
    }
    bilinear_kernel<<<1024, 256, 0, stream>>>(mm, stats, gamma, beta, out);
}